// Round 3
// baseline (447.209 us; speedup 1.0000x reference)
//
#include <hip/hip_runtime.h>

// ---------------------------------------------------------------------------
// EncoderLayer: x -> MHA(entmax1.5) -> +LN -> FFN(mish) -> +LN
// B=8 S=1024 D=512 H=8 hd=64 F=2048.  bf16 MFMA GEMMs, fp32 accum/epilogues.
// Round 3: fused flash-style attention (QK^T -> entmax -> PV in one kernel,
// score strip LDS-resident) replaces scores GEMM + entmax + PV GEMM.
// ---------------------------------------------------------------------------

typedef float f32x4 __attribute__((ext_vector_type(4)));
typedef __bf16 b8 __attribute__((ext_vector_type(8)));

#define DEV static __device__ __forceinline__

DEV unsigned short f2bf(float f) {
  unsigned u = __float_as_uint(f);
  u += 0x7fffu + ((u >> 16) & 1u);   // RNE
  return (unsigned short)(u >> 16);
}
DEV float bf2f(unsigned short b) { return __uint_as_float(((unsigned)b) << 16); }

DEV float mishf(float x) {
  if (x > 20.f) return x;
  float e = __expf(x);
  float u = 1.f + e;
  u *= u;
  return x * ((u - 1.f) / (u + 1.f));
}

DEV void async16(const void* g, void* l) {
  __builtin_amdgcn_global_load_lds(
      (const __attribute__((address_space(1))) unsigned int*)g,
      (__attribute__((address_space(3))) unsigned int*)l, 16, 0, 0);
}

// ---------------------------------------------------------------------------
// Generic MFMA GEMM:  C[M,N] = alpha * A[M,K] * Bt[N,K]^T (+bias) (+mish)
// (unchanged from round 2 — verified)
// ---------------------------------------------------------------------------
template <int WM, int WN, int EPI, bool OUTBF>
__global__ __launch_bounds__(256) void gemm_bt(
    const unsigned short* __restrict__ A, const unsigned short* __restrict__ Bt,
    const float* __restrict__ bias, void* __restrict__ Cp,
    int K, int lda, int ldb, int ldc,
    long sA1, long sA2, long sB1, long sB2, long sC1, long sC2,
    int hdiv, float alpha) {
  constexpr int BM = WM * 64, BN = WN * 64;
  __shared__ unsigned short smA[BM * 32];
  __shared__ unsigned short smB[BN * 32];

  const int tid = threadIdx.x;
  const int lane = tid & 63;
  const int z = blockIdx.z;
  const long zi = z / hdiv, zr = z % hdiv;
  const unsigned short* Ab = A + zi * sA1 + zr * sA2 + (long)blockIdx.x * BM * lda;
  const unsigned short* Bb = Bt + zi * sB1 + zr * sB2 + (long)blockIdx.y * BN * ldb;

  int siA[WM];
  const unsigned short* gA[WM];
#pragma unroll
  for (int q = 0; q < WM; ++q) {
    int si = q * 256 + tid;
    int m = si >> 2, s = si & 3, g = s ^ ((m >> 1) & 3);
    siA[q] = si;
    gA[q] = Ab + (long)m * lda + g * 8;
  }
  int siB[WN];
  const unsigned short* gB[WN];
#pragma unroll
  for (int q = 0; q < WN; ++q) {
    int si = q * 256 + tid;
    int m = si >> 2, s = si & 3, g = s ^ ((m >> 1) & 3);
    siB[q] = si;
    gB[q] = Bb + (long)m * ldb + g * 8;
  }

  const int w = tid >> 6;
  const int wr = w / WN, wc = w % WN;
  const int fm = lane & 15, fg = lane >> 4;

  int aOff[4], bOff[4];
#pragma unroll
  for (int i = 0; i < 4; ++i) {
    int m = wr * 64 + i * 16 + fm;
    aOff[i] = (m * 4 + (fg ^ ((m >> 1) & 3))) * 8;
    int n = wc * 64 + i * 16 + fm;
    bOff[i] = (n * 4 + (fg ^ ((n >> 1) & 3))) * 8;
  }

  f32x4 acc[4][4];
#pragma unroll
  for (int i = 0; i < 4; ++i)
#pragma unroll
    for (int j = 0; j < 4; ++j) acc[i][j] = (f32x4){0.f, 0.f, 0.f, 0.f};

  for (int k0 = 0; k0 < K; k0 += 32) {
    __syncthreads();
#pragma unroll
    for (int q = 0; q < WM; ++q) async16(gA[q] + k0, (void*)&smA[siA[q] * 8]);
#pragma unroll
    for (int q = 0; q < WN; ++q) async16(gB[q] + k0, (void*)&smB[siB[q] * 8]);
    __syncthreads();

    b8 aF[4], bF[4];
#pragma unroll
    for (int i = 0; i < 4; ++i) aF[i] = *(const b8*)&smA[aOff[i]];
#pragma unroll
    for (int j = 0; j < 4; ++j) bF[j] = *(const b8*)&smB[bOff[j]];
#pragma unroll
    for (int i = 0; i < 4; ++i)
#pragma unroll
      for (int j = 0; j < 4; ++j)
        acc[i][j] = __builtin_amdgcn_mfma_f32_16x16x32_bf16(aF[i], bF[j], acc[i][j], 0, 0, 0);
  }

  const long cbase = zi * sC1 + zr * sC2;
  const int row0 = blockIdx.x * BM + wr * 64 + fg * 4;
  const int col0 = blockIdx.y * BN + wc * 64 + fm;
#pragma unroll
  for (int i = 0; i < 4; ++i) {
#pragma unroll
    for (int j = 0; j < 4; ++j) {
      const int col = col0 + j * 16;
      float bv = (EPI >= 1) ? bias[col] : 0.f;
#pragma unroll
      for (int r = 0; r < 4; ++r) {
        const int row = row0 + i * 16 + r;
        float v = acc[i][j][r] * alpha + bv;
        if (EPI == 2) v = mishf(v);
        const long idx = cbase + (long)row * ldc + col;
        if constexpr (OUTBF)
          ((unsigned short*)Cp)[idx] = f2bf(v);
        else
          ((float*)Cp)[idx] = v;
      }
    }
  }
}

// ---------------------------------------------------------------------------
// Fused attention for one (b,h) x 32 Q-rows:
//   phase A: scores z = (Q K^T)/16 chunk-by-chunk -> bf16 LDS strip [32][1032]
//   phase B: entmax-1.5 per row in place (Newton from below, 2 rows/wave pass)
//   phase C: O = P @ V via Vt chunks -> bf16 global attn buffer
// ---------------------------------------------------------------------------
__global__ __launch_bounds__(256, 2) void fused_attn(
    const unsigned short* __restrict__ Qg, const unsigned short* __restrict__ Kg,
    const unsigned short* __restrict__ Vt, unsigned short* __restrict__ Og) {
  constexpr int LDP = 1032;  // strip leading dim (pad 8 -> 4-bank row stride)
  __shared__ unsigned short sP[32 * LDP];   // 66048 B
  __shared__ unsigned short sQ[32 * 64];    // 4096 B
  __shared__ unsigned short sKV[64 * 64];   // 8192 B  (K chunk, then Vt chunk)

  const int tid = threadIdx.x, lane = tid & 63, wv = tid >> 6;
  const int fm = lane & 15, fg = lane >> 4;
  const int qt = blockIdx.x, bh = blockIdx.y;
  const int b = bh >> 3, h = bh & 7;
  const long qkBase = (long)b * 1024 * 512 + h * 64;  // into [8192][512] Q/K
  const long vtBase = (long)bh * 64 * 1024;           // into [(bh)][64][1024] Vt

  // stage Q tile (32x64), plain row-major: slot = tid
  {
    const unsigned short* Qp = Qg + qkBase + (long)qt * 32 * 512;
    int m = tid >> 3, s = tid & 7;
    async16(Qp + m * 512 + s * 8, &sQ[tid * 8]);
  }

  // K/V chunk slot descriptors (swizzled: slot s holds global group s^(m&7))
  int mK[2], gK[2];
#pragma unroll
  for (int q = 0; q < 2; ++q) {
    int si = q * 256 + tid;
    mK[q] = si >> 3;
    gK[q] = (si & 7) ^ (mK[q] & 7);
  }

  b8 aQ[2][2];
  const int n = wv * 16 + fm;  // chunk-local B row (K-row / Vt-row)
  int bOffK[2];
#pragma unroll
  for (int k = 0; k < 2; ++k) bOffK[k] = n * 64 + ((k * 4 + fg) ^ (n & 7)) * 8;

  // ---------------- phase A ----------------
  for (int c = 0; c < 16; ++c) {
    __syncthreads();  // protect sKV from previous chunk's readers
#pragma unroll
    for (int q = 0; q < 2; ++q)
      async16(Kg + qkBase + (long)(c * 64 + mK[q]) * 512 + gK[q] * 8,
              &sKV[(q * 256 + tid) * 8]);
    __syncthreads();  // staging complete (also drains Q stage at c==0)

    if (c == 0) {
#pragma unroll
      for (int i = 0; i < 2; ++i)
#pragma unroll
        for (int k = 0; k < 2; ++k)
          aQ[i][k] = *(const b8*)&sQ[(i * 16 + fm) * 64 + k * 32 + fg * 8];
    }

    b8 bK[2];
#pragma unroll
    for (int k = 0; k < 2; ++k) bK[k] = *(const b8*)&sKV[bOffK[k]];

    f32x4 a0 = (f32x4){0.f, 0.f, 0.f, 0.f}, a1 = (f32x4){0.f, 0.f, 0.f, 0.f};
#pragma unroll
    for (int k = 0; k < 2; ++k) {
      a0 = __builtin_amdgcn_mfma_f32_16x16x32_bf16(aQ[0][k], bK[k], a0, 0, 0, 0);
      a1 = __builtin_amdgcn_mfma_f32_16x16x32_bf16(aQ[1][k], bK[k], a1, 0, 0, 0);
    }
    const int col = c * 64 + wv * 16 + fm;
#pragma unroll
    for (int r = 0; r < 4; ++r) {
      sP[(fg * 4 + r) * LDP + col] = f2bf(a0[r] * (1.f / 16.f));
      sP[(16 + fg * 4 + r) * LDP + col] = f2bf(a1[r] * (1.f / 16.f));
    }
  }
  __syncthreads();  // strip complete (all waves wrote all rows' col-slices)

  // ---------------- phase B: entmax rows (2 rows per pass) ----------------
  for (int pass = 0; pass < 4; ++pass) {
    unsigned short* pa = &sP[(wv * 8 + pass * 2) * LDP];
    unsigned short* pb = pa + LDP;
    union { uint4 v; unsigned short u[8]; } t0, t1, t2, t3;
    t0.v = *(const uint4*)(pa + lane * 16);
    t1.v = *(const uint4*)(pa + lane * 16 + 8);
    t2.v = *(const uint4*)(pb + lane * 16);
    t3.v = *(const uint4*)(pb + lane * 16 + 8);
    float za[16], zb[16];
#pragma unroll
    for (int i = 0; i < 8; ++i) {
      za[i] = bf2f(t0.u[i]);
      za[8 + i] = bf2f(t1.u[i]);
      zb[i] = bf2f(t2.u[i]);
      zb[8 + i] = bf2f(t3.u[i]);
    }
    float ma = za[0], mb = zb[0];
#pragma unroll
    for (int i = 1; i < 16; ++i) {
      ma = fmaxf(ma, za[i]);
      mb = fmaxf(mb, zb[i]);
    }
#pragma unroll
    for (int o = 32; o; o >>= 1) {
      ma = fmaxf(ma, __shfl_xor(ma, o));
      mb = fmaxf(mb, __shfl_xor(mb, o));
    }
#pragma unroll
    for (int i = 0; i < 16; ++i) {
      za[i] -= ma;
      zb[i] -= mb;
    }
    float ta = -1.f, tb = -1.f;
    for (int it = 0; it < 16; ++it) {
      float s1a = 0.f, s2a = 0.f, s1b = 0.f, s2b = 0.f;
#pragma unroll
      for (int i = 0; i < 16; ++i) {
        float ha = fmaxf(za[i] - ta, 0.f);
        float hb = fmaxf(zb[i] - tb, 0.f);
        s1a += ha;
        s2a = fmaf(ha, ha, s2a);
        s1b += hb;
        s2b = fmaf(hb, hb, s2b);
      }
#pragma unroll
      for (int o = 32; o; o >>= 1) {
        s1a += __shfl_xor(s1a, o);
        s2a += __shfl_xor(s2a, o);
        s1b += __shfl_xor(s1b, o);
        s2b += __shfl_xor(s2b, o);
      }
      float exa = s2a - 1.f, exb = s2b - 1.f;
      if (exa < 1e-4f && exb < 1e-4f) break;
      ta += exa / (2.f * s1a);  // from-below Newton: post-convergence moves ~0
      tb += exb / (2.f * s1b);
    }
#pragma unroll
    for (int i = 0; i < 8; ++i) {
      float h0 = fmaxf(za[i] - ta, 0.f);
      float h1 = fmaxf(za[8 + i] - ta, 0.f);
      float h2 = fmaxf(zb[i] - tb, 0.f);
      float h3 = fmaxf(zb[8 + i] - tb, 0.f);
      t0.u[i] = f2bf(h0 * h0);
      t1.u[i] = f2bf(h1 * h1);
      t2.u[i] = f2bf(h2 * h2);
      t3.u[i] = f2bf(h3 * h3);
    }
    *(uint4*)(pa + lane * 16) = t0.v;
    *(uint4*)(pa + lane * 16 + 8) = t1.v;
    *(uint4*)(pb + lane * 16) = t2.v;
    *(uint4*)(pb + lane * 16 + 8) = t3.v;
  }

  // ---------------- phase C: O = P @ V ----------------
  f32x4 o0 = (f32x4){0.f, 0.f, 0.f, 0.f}, o1 = (f32x4){0.f, 0.f, 0.f, 0.f};
  for (int c = 0; c < 16; ++c) {
    __syncthreads();  // c==0: phase B writes done; else: prev chunk readers done
#pragma unroll
    for (int q = 0; q < 2; ++q)
      async16(Vt + vtBase + (long)mK[q] * 1024 + c * 64 + gK[q] * 8,
              &sKV[(q * 256 + tid) * 8]);
    __syncthreads();

    b8 bV[2];
#pragma unroll
    for (int k = 0; k < 2; ++k) bV[k] = *(const b8*)&sKV[bOffK[k]];
#pragma unroll
    for (int k = 0; k < 2; ++k) {
      b8 aP0 = *(const b8*)&sP[fm * LDP + c * 64 + k * 32 + fg * 8];
      b8 aP1 = *(const b8*)&sP[(16 + fm) * LDP + c * 64 + k * 32 + fg * 8];
      o0 = __builtin_amdgcn_mfma_f32_16x16x32_bf16(aP0, bV[k], o0, 0, 0, 0);
      o1 = __builtin_amdgcn_mfma_f32_16x16x32_bf16(aP1, bV[k], o1, 0, 0, 0);
    }
  }

  const long orow0 = (long)b * 1024 + qt * 32;
  const int colg = h * 64 + wv * 16 + fm;
#pragma unroll
  for (int r = 0; r < 4; ++r) {
    Og[(orow0 + fg * 4 + r) * 512 + colg] = f2bf(o0[r]);
    Og[(orow0 + 16 + fg * 4 + r) * 512 + colg] = f2bf(o1[r]);
  }
}

// ---------------------------------------------------------------------------
// fp32 -> bf16 cast (vectorized)
// ---------------------------------------------------------------------------
__global__ __launch_bounds__(256) void cast_f2b(const float* __restrict__ in,
                                                unsigned short* __restrict__ out, long n) {
  long i = ((long)blockIdx.x * 256 + threadIdx.x) * 4;
  if (i >= n) return;
  float4 v = *(const float4*)&in[i];
  unsigned lo = (unsigned)f2bf(v.x) | ((unsigned)f2bf(v.y) << 16);
  unsigned hi = (unsigned)f2bf(v.z) | ((unsigned)f2bf(v.w) << 16);
  uint2 p;
  p.x = lo;
  p.y = hi;
  *(uint2*)&out[i] = p;
}

// ---------------------------------------------------------------------------
// Transpose fp32[R,C] (ldi) -> bf16[C,R] (ldo), 32x32 LDS tiles (weights)
// ---------------------------------------------------------------------------
__global__ __launch_bounds__(256) void transpose_f2b(const float* __restrict__ in,
                                                     unsigned short* __restrict__ out,
                                                     int ldi, int ldo) {
  __shared__ float t[32][33];
  const int tx = threadIdx.x & 31, ty = threadIdx.x >> 5;
  const int r0 = blockIdx.y * 32, c0 = blockIdx.x * 32;
#pragma unroll
  for (int q = 0; q < 4; ++q) {
    int r = ty + q * 8;
    t[r][tx] = in[(long)(r0 + r) * ldi + c0 + tx];
  }
  __syncthreads();
#pragma unroll
  for (int q = 0; q < 4; ++q) {
    int r = ty + q * 8;
    out[(long)(c0 + r) * ldo + r0 + tx] = f2bf(t[tx][r]);
  }
}

// bf16 batched transpose (for V -> V^T per (b,h))
__global__ __launch_bounds__(256) void transpose_b2b(const unsigned short* __restrict__ in,
                                                     unsigned short* __restrict__ out,
                                                     int ldi, int ldo, long i1, long i2,
                                                     long o1, long o2, int hdiv) {
  __shared__ unsigned short t[32][33];
  const int z = blockIdx.z;
  in += (long)(z / hdiv) * i1 + (long)(z % hdiv) * i2;
  out += (long)(z / hdiv) * o1 + (long)(z % hdiv) * o2;
  const int tx = threadIdx.x & 31, ty = threadIdx.x >> 5;
  const int r0 = blockIdx.y * 32, c0 = blockIdx.x * 32;
#pragma unroll
  for (int q = 0; q < 4; ++q) {
    int r = ty + q * 8;
    t[r][tx] = in[(long)(r0 + r) * ldi + c0 + tx];
  }
  __syncthreads();
#pragma unroll
  for (int q = 0; q < 4; ++q) {
    int r = ty + q * 8;
    out[(long)(c0 + r) * ldo + r0 + tx] = t[tx][r];
  }
}

// ---------------------------------------------------------------------------
// out = xin + LayerNorm(y)*g + be   (row length 512, 256 threads/row)
// ---------------------------------------------------------------------------
template <bool WB>
__global__ __launch_bounds__(256) void ln_res(const float* __restrict__ xin,
                                              const float* __restrict__ y,
                                              const float* __restrict__ g,
                                              const float* __restrict__ be,
                                              float* __restrict__ xo,
                                              unsigned short* __restrict__ xob) {
  const int row = blockIdx.x, tid = threadIdx.x, lane = tid & 63, wv = tid >> 6;
  const long base = (long)row * 512 + tid * 2;
  float2 v = *(const float2*)&y[base];
  float s1 = v.x + v.y, s2 = v.x * v.x + v.y * v.y;
  for (int o = 32; o; o >>= 1) {
    s1 += __shfl_xor(s1, o);
    s2 += __shfl_xor(s2, o);
  }
  __shared__ float red[4][2];
  if (lane == 0) {
    red[wv][0] = s1;
    red[wv][1] = s2;
  }
  __syncthreads();
  s1 = red[0][0] + red[1][0] + red[2][0] + red[3][0];
  s2 = red[0][1] + red[1][1] + red[2][1] + red[3][1];
  const float mu = s1 * (1.f / 512.f);
  const float rstd = rsqrtf(s2 * (1.f / 512.f) - mu * mu + 1e-5f);
  const int c = tid * 2;
  float2 xv = *(const float2*)&xin[base];
  float o0 = xv.x + (v.x - mu) * rstd * g[c] + be[c];
  float o1 = xv.y + (v.y - mu) * rstd * g[c + 1] + be[c + 1];
  float2 ov;
  ov.x = o0;
  ov.y = o1;
  *(float2*)&xo[base] = ov;
  if constexpr (WB) {
    unsigned pk = (unsigned)f2bf(o0) | ((unsigned)f2bf(o1) << 16);
    *(unsigned*)&xob[base] = pk;
  }
}

// ---------------------------------------------------------------------------
extern "C" void kernel_launch(void* const* d_in, const int* in_sizes, int n_in,
                              void* d_out, int out_size, void* d_ws, size_t ws_size,
                              hipStream_t stream) {
  const int B = 8, S = 1024, D = 512, H = 8, F = 2048;
  const int BS = B * S;  // 8192 rows

  const float* x = (const float*)d_in[0];
  const float* Wq = (const float*)d_in[1];
  const float* bq = (const float*)d_in[2];
  const float* Wk = (const float*)d_in[3];
  const float* bk = (const float*)d_in[4];
  const float* Wv = (const float*)d_in[5];
  const float* bv = (const float*)d_in[6];
  const float* Wo = (const float*)d_in[7];
  const float* bo = (const float*)d_in[8];
  const float* g1 = (const float*)d_in[9];
  const float* be1 = (const float*)d_in[10];
  const float* W1 = (const float*)d_in[11];
  const float* b1 = (const float*)d_in[12];
  const float* W2 = (const float*)d_in[13];
  const float* b2 = (const float*)d_in[14];
  const float* g2 = (const float*)d_in[15];
  const float* be2 = (const float*)d_in[16];
  float* out = (float*)d_out;

  char* w = (char*)d_ws;
  size_t off = 0;
  auto alloc = [&](size_t bytes) -> void* {
    void* p = w + off;
    off += bytes;
    off = (off + 255) & ~(size_t)255;
    return p;
  };

  unsigned short* xb = (unsigned short*)alloc((size_t)BS * D * 2);
  unsigned short* Wqt = (unsigned short*)alloc((size_t)D * D * 2);
  unsigned short* Wkt = (unsigned short*)alloc((size_t)D * D * 2);
  unsigned short* Wvt = (unsigned short*)alloc((size_t)D * D * 2);
  unsigned short* Wot = (unsigned short*)alloc((size_t)D * D * 2);
  unsigned short* W1t = (unsigned short*)alloc((size_t)F * D * 2);
  unsigned short* W2t = (unsigned short*)alloc((size_t)D * F * 2);
  unsigned short* Qb = (unsigned short*)alloc((size_t)BS * D * 2);
  unsigned short* Kb = (unsigned short*)alloc((size_t)BS * D * 2);
  unsigned short* Vb = (unsigned short*)alloc((size_t)BS * D * 2);
  unsigned short* Vt = (unsigned short*)alloc((size_t)BS * D * 2);
  float* yb = (float*)alloc((size_t)BS * D * 4);
  float* x1 = (float*)alloc((size_t)BS * D * 4);
  unsigned short* hb = (unsigned short*)alloc((size_t)BS * F * 2);
  unsigned short* attn = Vb;  // reuse: Vb dead after transpose_b2b
  unsigned short* x1b = xb;   // reuse: xb dead after QKV GEMMs

  const long SD = (long)S * D;        // 524288
  const long HDS = (long)H * 64 * S;  // per-b Vt stride

  // 1) casts + weight transposes (bf16, N x K form)
  cast_f2b<<<(BS * D) / 1024, 256, 0, stream>>>(x, xb, (long)BS * D);
  transpose_f2b<<<dim3(16, 16, 1), 256, 0, stream>>>(Wq, Wqt, D, D);
  transpose_f2b<<<dim3(16, 16, 1), 256, 0, stream>>>(Wk, Wkt, D, D);
  transpose_f2b<<<dim3(16, 16, 1), 256, 0, stream>>>(Wv, Wvt, D, D);
  transpose_f2b<<<dim3(16, 16, 1), 256, 0, stream>>>(Wo, Wot, D, D);
  transpose_f2b<<<dim3(F / 32, D / 32, 1), 256, 0, stream>>>(W1, W1t, F, D);
  transpose_f2b<<<dim3(D / 32, F / 32, 1), 256, 0, stream>>>(W2, W2t, D, F);

  // 2) Q,K,V projections (bf16 out)
  gemm_bt<2, 2, 1, true><<<dim3(BS / 128, D / 128, 1), 256, 0, stream>>>(
      xb, Wqt, bq, Qb, D, D, D, D, 0, 0, 0, 0, 0, 0, 1, 1.f);
  gemm_bt<2, 2, 1, true><<<dim3(BS / 128, D / 128, 1), 256, 0, stream>>>(
      xb, Wkt, bk, Kb, D, D, D, D, 0, 0, 0, 0, 0, 0, 1, 1.f);
  gemm_bt<2, 2, 1, true><<<dim3(BS / 128, D / 128, 1), 256, 0, stream>>>(
      xb, Wvt, bv, Vb, D, D, D, D, 0, 0, 0, 0, 0, 0, 1, 1.f);

  // 3) V -> Vt[(b,h), d, s]
  transpose_b2b<<<dim3(2, 32, B * H), 256, 0, stream>>>(Vb, Vt, D, S, SD, 64, HDS,
                                                        (long)64 * S, H);

  // 4-6) fused scores -> entmax -> PV
  fused_attn<<<dim3(32, 64), 256, 0, stream>>>(Qb, Kb, Vt, attn);

  // 7) y = attn_out @ Wo + bo (fp32)
  gemm_bt<2, 2, 1, false><<<dim3(BS / 128, D / 128, 1), 256, 0, stream>>>(
      attn, Wot, bo, yb, D, D, D, D, 0, 0, 0, 0, 0, 0, 1, 1.f);

  // 8) x1 = x + LN(y)*g1 + be1  (fp32 + bf16 copy)
  ln_res<true><<<BS, 256, 0, stream>>>(x, yb, g1, be1, x1, x1b);

  // 9) h = mish(x1 @ W1 + b1) (bf16)
  gemm_bt<2, 2, 2, true><<<dim3(BS / 128, F / 128, 1), 256, 0, stream>>>(
      x1b, W1t, b1, hb, D, D, D, F, 0, 0, 0, 0, 0, 0, 1, 1.f);

  // 10) y2 = h @ W2 + b2 (fp32, reuse yb)
  gemm_bt<2, 2, 1, false><<<dim3(BS / 128, D / 128, 1), 256, 0, stream>>>(
      hb, W2t, b2, yb, F, F, F, D, 0, 0, 0, 0, 0, 0, 1, 1.f);

  // 11) out = x1 + LN(y2)*g2 + be2
  ln_res<false><<<BS, 256, 0, stream>>>(x1, yb, g2, be2, out, nullptr);
}

// Round 4
// 424.483 us; speedup vs baseline: 1.0535x; 1.0535x over previous
//
#include <hip/hip_runtime.h>

// ---------------------------------------------------------------------------
// EncoderLayer: x -> MHA(entmax1.5) -> +LN -> FFN(mish) -> +LN
// B=8 S=1024 D=512 H=8 hd=64 F=2048.  bf16 MFMA GEMMs, fp32 accum/epilogues.
// Round 4: fused attention with 16-row strips (43 KB LDS -> 3 blocks/CU),
// conflict-free phase-B access, merged QKV projection (N=1536).
// ---------------------------------------------------------------------------

typedef float f32x4 __attribute__((ext_vector_type(4)));
typedef __bf16 b8 __attribute__((ext_vector_type(8)));

#define DEV static __device__ __forceinline__

DEV unsigned short f2bf(float f) {
  unsigned u = __float_as_uint(f);
  u += 0x7fffu + ((u >> 16) & 1u);   // RNE
  return (unsigned short)(u >> 16);
}
DEV float bf2f(unsigned short b) { return __uint_as_float(((unsigned)b) << 16); }

DEV float mishf(float x) {
  if (x > 20.f) return x;
  float e = __expf(x);
  float u = 1.f + e;
  u *= u;
  return x * ((u - 1.f) / (u + 1.f));
}

DEV void async16(const void* g, void* l) {
  __builtin_amdgcn_global_load_lds(
      (const __attribute__((address_space(1))) unsigned int*)g,
      (__attribute__((address_space(3))) unsigned int*)l, 16, 0, 0);
}

// ---------------------------------------------------------------------------
// Generic MFMA GEMM:  C[M,N] = alpha * A[M,K] * Bt[N,K]^T (+bias) (+mish)
// (unchanged from round 2 — verified)
// ---------------------------------------------------------------------------
template <int WM, int WN, int EPI, bool OUTBF>
__global__ __launch_bounds__(256) void gemm_bt(
    const unsigned short* __restrict__ A, const unsigned short* __restrict__ Bt,
    const float* __restrict__ bias, void* __restrict__ Cp,
    int K, int lda, int ldb, int ldc,
    long sA1, long sA2, long sB1, long sB2, long sC1, long sC2,
    int hdiv, float alpha) {
  constexpr int BM = WM * 64, BN = WN * 64;
  __shared__ unsigned short smA[BM * 32];
  __shared__ unsigned short smB[BN * 32];

  const int tid = threadIdx.x;
  const int lane = tid & 63;
  const int z = blockIdx.z;
  const long zi = z / hdiv, zr = z % hdiv;
  const unsigned short* Ab = A + zi * sA1 + zr * sA2 + (long)blockIdx.x * BM * lda;
  const unsigned short* Bb = Bt + zi * sB1 + zr * sB2 + (long)blockIdx.y * BN * ldb;

  int siA[WM];
  const unsigned short* gA[WM];
#pragma unroll
  for (int q = 0; q < WM; ++q) {
    int si = q * 256 + tid;
    int m = si >> 2, s = si & 3, g = s ^ ((m >> 1) & 3);
    siA[q] = si;
    gA[q] = Ab + (long)m * lda + g * 8;
  }
  int siB[WN];
  const unsigned short* gB[WN];
#pragma unroll
  for (int q = 0; q < WN; ++q) {
    int si = q * 256 + tid;
    int m = si >> 2, s = si & 3, g = s ^ ((m >> 1) & 3);
    siB[q] = si;
    gB[q] = Bb + (long)m * ldb + g * 8;
  }

  const int w = tid >> 6;
  const int wr = w / WN, wc = w % WN;
  const int fm = lane & 15, fg = lane >> 4;

  int aOff[4], bOff[4];
#pragma unroll
  for (int i = 0; i < 4; ++i) {
    int m = wr * 64 + i * 16 + fm;
    aOff[i] = (m * 4 + (fg ^ ((m >> 1) & 3))) * 8;
    int n = wc * 64 + i * 16 + fm;
    bOff[i] = (n * 4 + (fg ^ ((n >> 1) & 3))) * 8;
  }

  f32x4 acc[4][4];
#pragma unroll
  for (int i = 0; i < 4; ++i)
#pragma unroll
    for (int j = 0; j < 4; ++j) acc[i][j] = (f32x4){0.f, 0.f, 0.f, 0.f};

  for (int k0 = 0; k0 < K; k0 += 32) {
    __syncthreads();
#pragma unroll
    for (int q = 0; q < WM; ++q) async16(gA[q] + k0, (void*)&smA[siA[q] * 8]);
#pragma unroll
    for (int q = 0; q < WN; ++q) async16(gB[q] + k0, (void*)&smB[siB[q] * 8]);
    __syncthreads();

    b8 aF[4], bF[4];
#pragma unroll
    for (int i = 0; i < 4; ++i) aF[i] = *(const b8*)&smA[aOff[i]];
#pragma unroll
    for (int j = 0; j < 4; ++j) bF[j] = *(const b8*)&smB[bOff[j]];
#pragma unroll
    for (int i = 0; i < 4; ++i)
#pragma unroll
      for (int j = 0; j < 4; ++j)
        acc[i][j] = __builtin_amdgcn_mfma_f32_16x16x32_bf16(aF[i], bF[j], acc[i][j], 0, 0, 0);
  }

  const long cbase = zi * sC1 + zr * sC2;
  const int row0 = blockIdx.x * BM + wr * 64 + fg * 4;
  const int col0 = blockIdx.y * BN + wc * 64 + fm;
#pragma unroll
  for (int i = 0; i < 4; ++i) {
#pragma unroll
    for (int j = 0; j < 4; ++j) {
      const int col = col0 + j * 16;
      float bv = (EPI >= 1) ? bias[col] : 0.f;
#pragma unroll
      for (int r = 0; r < 4; ++r) {
        const int row = row0 + i * 16 + r;
        float v = acc[i][j][r] * alpha + bv;
        if (EPI == 2) v = mishf(v);
        const long idx = cbase + (long)row * ldc + col;
        if constexpr (OUTBF)
          ((unsigned short*)Cp)[idx] = f2bf(v);
        else
          ((float*)Cp)[idx] = v;
      }
    }
  }
}

// ---------------------------------------------------------------------------
// Fused attention, one block = one (b,h) x 16 Q-rows. QKV packed [8192][1536]
// (Q at col 0, K at col 512, V handled via Vt).
//   phase A: z = (Q K^T)/16 -> bf16 LDS strip [16][1032]
//   phase B: entmax-1.5 per row in place (lane-contiguous, conflict-free)
//   phase C: O = P @ V -> bf16 global
// LDS 43.3 KB -> 3 blocks/CU.
// ---------------------------------------------------------------------------
__global__ __launch_bounds__(256) void fused_attn(
    const unsigned short* __restrict__ QKV, const unsigned short* __restrict__ Vt,
    unsigned short* __restrict__ Og) {
  constexpr int LDP = 1032;
  __shared__ unsigned short sP[16 * LDP];   // 33024 B
  __shared__ unsigned short sQ[16 * 64];    // 2048 B
  __shared__ unsigned short sKV[64 * 64];   // 8192 B

  const int tid = threadIdx.x, lane = tid & 63, wv = tid >> 6;
  const int fm = lane & 15, fg = lane >> 4;
  const int qt = blockIdx.x, bh = blockIdx.y;
  const int b = bh >> 3, h = bh & 7;
  const long qkBase = (long)b * 1024 * 1536 + h * 64;  // head col block
  const long vtBase = (long)bh * 64 * 1024;

  // stage Q tile (16x64): 128 slots of 16 B, waves 0-1 only (wave-granular)
  if (tid < 128) {
    const unsigned short* Qp = QKV + qkBase + (long)qt * 16 * 1536;
    int m = tid >> 3, s = tid & 7;
    async16(Qp + m * 1536 + s * 8, &sQ[tid * 8]);
  }

  // K/Vt chunk slot descriptors (swizzled: slot s holds global group s^(m&7))
  int mK[2], gK[2];
#pragma unroll
  for (int q = 0; q < 2; ++q) {
    int si = q * 256 + tid;
    mK[q] = si >> 3;
    gK[q] = (si & 7) ^ (mK[q] & 7);
  }

  b8 aQ[2];
  const int n = wv * 16 + fm;  // chunk-local B row (key-row / Vt d-row)
  int bOffK[2];
#pragma unroll
  for (int k = 0; k < 2; ++k) bOffK[k] = n * 64 + ((k * 4 + fg) ^ (n & 7)) * 8;

  // ---------------- phase A ----------------
  const unsigned short* Kp = QKV + qkBase + 512;
  for (int c = 0; c < 16; ++c) {
    __syncthreads();
#pragma unroll
    for (int q = 0; q < 2; ++q)
      async16(Kp + (long)(c * 64 + mK[q]) * 1536 + gK[q] * 8,
              &sKV[(q * 256 + tid) * 8]);
    __syncthreads();  // vmcnt(0): staging complete (drains Q stage at c==0)

    if (c == 0) {
#pragma unroll
      for (int k = 0; k < 2; ++k)
        aQ[k] = *(const b8*)&sQ[fm * 64 + k * 32 + fg * 8];
    }

    b8 bK[2];
#pragma unroll
    for (int k = 0; k < 2; ++k) bK[k] = *(const b8*)&sKV[bOffK[k]];

    f32x4 a0 = (f32x4){0.f, 0.f, 0.f, 0.f};
#pragma unroll
    for (int k = 0; k < 2; ++k)
      a0 = __builtin_amdgcn_mfma_f32_16x16x32_bf16(aQ[k], bK[k], a0, 0, 0, 0);

    const int col = c * 64 + wv * 16 + fm;
#pragma unroll
    for (int r = 0; r < 4; ++r)
      sP[(fg * 4 + r) * LDP + col] = f2bf(a0[r] * (1.f / 16.f));
  }
  __syncthreads();  // strip complete

  // ---------------- phase B: entmax rows (4 waves x 2 passes x 2 rows) -----
  // lane-contiguous 16B accesses: lane covers [lane*8, lane*8+8) and
  // [512+lane*8, ...) shorts of the row -> conflict-free b128.
  for (int pass = 0; pass < 2; ++pass) {
    unsigned short* pa = &sP[(wv * 4 + pass * 2) * LDP];
    unsigned short* pb = pa + LDP;
    union { uint4 v; unsigned short u[8]; } t0, t1, t2, t3;
    t0.v = *(const uint4*)(pa + lane * 8);
    t1.v = *(const uint4*)(pa + 512 + lane * 8);
    t2.v = *(const uint4*)(pb + lane * 8);
    t3.v = *(const uint4*)(pb + 512 + lane * 8);
    float za[16], zb[16];
#pragma unroll
    for (int i = 0; i < 8; ++i) {
      za[i] = bf2f(t0.u[i]);
      za[8 + i] = bf2f(t1.u[i]);
      zb[i] = bf2f(t2.u[i]);
      zb[8 + i] = bf2f(t3.u[i]);
    }
    float ma = za[0], mb = zb[0];
#pragma unroll
    for (int i = 1; i < 16; ++i) {
      ma = fmaxf(ma, za[i]);
      mb = fmaxf(mb, zb[i]);
    }
#pragma unroll
    for (int o = 32; o; o >>= 1) {
      ma = fmaxf(ma, __shfl_xor(ma, o));
      mb = fmaxf(mb, __shfl_xor(mb, o));
    }
#pragma unroll
    for (int i = 0; i < 16; ++i) {
      za[i] -= ma;
      zb[i] -= mb;
    }
    float ta = -1.f, tb = -1.f;
    for (int it = 0; it < 16; ++it) {
      float s1a = 0.f, s2a = 0.f, s1b = 0.f, s2b = 0.f;
#pragma unroll
      for (int i = 0; i < 16; ++i) {
        float ha = fmaxf(za[i] - ta, 0.f);
        float hb = fmaxf(zb[i] - tb, 0.f);
        s1a += ha;
        s2a = fmaf(ha, ha, s2a);
        s1b += hb;
        s2b = fmaf(hb, hb, s2b);
      }
#pragma unroll
      for (int o = 32; o; o >>= 1) {
        s1a += __shfl_xor(s1a, o);
        s2a += __shfl_xor(s2a, o);
        s1b += __shfl_xor(s1b, o);
        s2b += __shfl_xor(s2b, o);
      }
      float exa = s2a - 1.f, exb = s2b - 1.f;
      if (exa < 1e-4f && exb < 1e-4f) break;
      ta += exa / (2.f * s1a);
      tb += exb / (2.f * s1b);
    }
#pragma unroll
    for (int i = 0; i < 8; ++i) {
      float h0 = fmaxf(za[i] - ta, 0.f);
      float h1 = fmaxf(za[8 + i] - ta, 0.f);
      float h2 = fmaxf(zb[i] - tb, 0.f);
      float h3 = fmaxf(zb[8 + i] - tb, 0.f);
      t0.u[i] = f2bf(h0 * h0);
      t1.u[i] = f2bf(h1 * h1);
      t2.u[i] = f2bf(h2 * h2);
      t3.u[i] = f2bf(h3 * h3);
    }
    *(uint4*)(pa + lane * 8) = t0.v;
    *(uint4*)(pa + 512 + lane * 8) = t1.v;
    *(uint4*)(pb + lane * 8) = t2.v;
    *(uint4*)(pb + 512 + lane * 8) = t3.v;
  }

  // ---------------- phase C: O = P @ V ----------------
  f32x4 o0 = (f32x4){0.f, 0.f, 0.f, 0.f};
  for (int c = 0; c < 16; ++c) {
    __syncthreads();  // c==0: phase B done; else: prev chunk readers done
#pragma unroll
    for (int q = 0; q < 2; ++q)
      async16(Vt + vtBase + (long)mK[q] * 1024 + c * 64 + gK[q] * 8,
              &sKV[(q * 256 + tid) * 8]);
    __syncthreads();

    b8 bV[2];
#pragma unroll
    for (int k = 0; k < 2; ++k) bV[k] = *(const b8*)&sKV[bOffK[k]];
#pragma unroll
    for (int k = 0; k < 2; ++k) {
      b8 aP = *(const b8*)&sP[fm * LDP + c * 64 + k * 32 + fg * 8];
      o0 = __builtin_amdgcn_mfma_f32_16x16x32_bf16(aP, bV[k], o0, 0, 0, 0);
    }
  }

  const long orow0 = (long)b * 1024 + qt * 16;
  const int colg = h * 64 + wv * 16 + fm;
#pragma unroll
  for (int r = 0; r < 4; ++r)
    Og[(orow0 + fg * 4 + r) * 512 + colg] = f2bf(o0[r]);
}

// ---------------------------------------------------------------------------
// fp32 -> bf16 cast (vectorized)
// ---------------------------------------------------------------------------
__global__ __launch_bounds__(256) void cast_f2b(const float* __restrict__ in,
                                                unsigned short* __restrict__ out, long n) {
  long i = ((long)blockIdx.x * 256 + threadIdx.x) * 4;
  if (i >= n) return;
  float4 v = *(const float4*)&in[i];
  unsigned lo = (unsigned)f2bf(v.x) | ((unsigned)f2bf(v.y) << 16);
  unsigned hi = (unsigned)f2bf(v.z) | ((unsigned)f2bf(v.w) << 16);
  uint2 p;
  p.x = lo;
  p.y = hi;
  *(uint2*)&out[i] = p;
}

// concat 3 bias vectors of 512 into one 1536
__global__ __launch_bounds__(256) void concat3(const float* __restrict__ a,
                                               const float* __restrict__ b,
                                               const float* __restrict__ c,
                                               float* __restrict__ o) {
  int i = blockIdx.x * 256 + threadIdx.x;
  if (i < 512) o[i] = a[i];
  else if (i < 1024) o[i] = b[i - 512];
  else if (i < 1536) o[i] = c[i - 1024];
}

// ---------------------------------------------------------------------------
// Transpose fp32[R,C] (ldi) -> bf16[C,R] (ldo), 32x32 LDS tiles (weights)
// ---------------------------------------------------------------------------
__global__ __launch_bounds__(256) void transpose_f2b(const float* __restrict__ in,
                                                     unsigned short* __restrict__ out,
                                                     int ldi, int ldo) {
  __shared__ float t[32][33];
  const int tx = threadIdx.x & 31, ty = threadIdx.x >> 5;
  const int r0 = blockIdx.y * 32, c0 = blockIdx.x * 32;
#pragma unroll
  for (int q = 0; q < 4; ++q) {
    int r = ty + q * 8;
    t[r][tx] = in[(long)(r0 + r) * ldi + c0 + tx];
  }
  __syncthreads();
#pragma unroll
  for (int q = 0; q < 4; ++q) {
    int r = ty + q * 8;
    out[(long)(c0 + r) * ldo + r0 + tx] = f2bf(t[tx][r]);
  }
}

// bf16 batched transpose (for V -> V^T per (b,h))
__global__ __launch_bounds__(256) void transpose_b2b(const unsigned short* __restrict__ in,
                                                     unsigned short* __restrict__ out,
                                                     int ldi, int ldo, long i1, long i2,
                                                     long o1, long o2, int hdiv) {
  __shared__ unsigned short t[32][33];
  const int z = blockIdx.z;
  in += (long)(z / hdiv) * i1 + (long)(z % hdiv) * i2;
  out += (long)(z / hdiv) * o1 + (long)(z % hdiv) * o2;
  const int tx = threadIdx.x & 31, ty = threadIdx.x >> 5;
  const int r0 = blockIdx.y * 32, c0 = blockIdx.x * 32;
#pragma unroll
  for (int q = 0; q < 4; ++q) {
    int r = ty + q * 8;
    t[r][tx] = in[(long)(r0 + r) * ldi + c0 + tx];
  }
  __syncthreads();
#pragma unroll
  for (int q = 0; q < 4; ++q) {
    int r = ty + q * 8;
    out[(long)(c0 + r) * ldo + r0 + tx] = t[tx][r];
  }
}

// ---------------------------------------------------------------------------
// out = xin + LayerNorm(y)*g + be   (row length 512, 256 threads/row)
// ---------------------------------------------------------------------------
template <bool WB>
__global__ __launch_bounds__(256) void ln_res(const float* __restrict__ xin,
                                              const float* __restrict__ y,
                                              const float* __restrict__ g,
                                              const float* __restrict__ be,
                                              float* __restrict__ xo,
                                              unsigned short* __restrict__ xob) {
  const int row = blockIdx.x, tid = threadIdx.x, lane = tid & 63, wv = tid >> 6;
  const long base = (long)row * 512 + tid * 2;
  float2 v = *(const float2*)&y[base];
  float s1 = v.x + v.y, s2 = v.x * v.x + v.y * v.y;
  for (int o = 32; o; o >>= 1) {
    s1 += __shfl_xor(s1, o);
    s2 += __shfl_xor(s2, o);
  }
  __shared__ float red[4][2];
  if (lane == 0) {
    red[wv][0] = s1;
    red[wv][1] = s2;
  }
  __syncthreads();
  s1 = red[0][0] + red[1][0] + red[2][0] + red[3][0];
  s2 = red[0][1] + red[1][1] + red[2][1] + red[3][1];
  const float mu = s1 * (1.f / 512.f);
  const float rstd = rsqrtf(s2 * (1.f / 512.f) - mu * mu + 1e-5f);
  const int c = tid * 2;
  float2 xv = *(const float2*)&xin[base];
  float o0 = xv.x + (v.x - mu) * rstd * g[c] + be[c];
  float o1 = xv.y + (v.y - mu) * rstd * g[c + 1] + be[c + 1];
  float2 ov;
  ov.x = o0;
  ov.y = o1;
  *(float2*)&xo[base] = ov;
  if constexpr (WB) {
    unsigned pk = (unsigned)f2bf(o0) | ((unsigned)f2bf(o1) << 16);
    *(unsigned*)&xob[base] = pk;
  }
}

// ---------------------------------------------------------------------------
extern "C" void kernel_launch(void* const* d_in, const int* in_sizes, int n_in,
                              void* d_out, int out_size, void* d_ws, size_t ws_size,
                              hipStream_t stream) {
  const int B = 8, S = 1024, D = 512, F = 2048;
  const int BS = B * S;  // 8192 rows
  const int N3 = 3 * D;  // 1536

  const float* x = (const float*)d_in[0];
  const float* Wq = (const float*)d_in[1];
  const float* bq = (const float*)d_in[2];
  const float* Wk = (const float*)d_in[3];
  const float* bk = (const float*)d_in[4];
  const float* Wv = (const float*)d_in[5];
  const float* bv = (const float*)d_in[6];
  const float* Wo = (const float*)d_in[7];
  const float* bo = (const float*)d_in[8];
  const float* g1 = (const float*)d_in[9];
  const float* be1 = (const float*)d_in[10];
  const float* W1 = (const float*)d_in[11];
  const float* b1 = (const float*)d_in[12];
  const float* W2 = (const float*)d_in[13];
  const float* b2 = (const float*)d_in[14];
  const float* g2 = (const float*)d_in[15];
  const float* be2 = (const float*)d_in[16];
  float* out = (float*)d_out;

  char* w = (char*)d_ws;
  size_t off = 0;
  auto alloc = [&](size_t bytes) -> void* {
    void* p = w + off;
    off += bytes;
    off = (off + 255) & ~(size_t)255;
    return p;
  };

  unsigned short* xb = (unsigned short*)alloc((size_t)BS * D * 2);
  unsigned short* Wqkvt = (unsigned short*)alloc((size_t)N3 * D * 2);
  unsigned short* Wot = (unsigned short*)alloc((size_t)D * D * 2);
  unsigned short* W1t = (unsigned short*)alloc((size_t)F * D * 2);
  unsigned short* W2t = (unsigned short*)alloc((size_t)D * F * 2);
  float* bqkv = (float*)alloc((size_t)N3 * 4);
  unsigned short* QKVb = (unsigned short*)alloc((size_t)BS * N3 * 2);
  unsigned short* Vt = (unsigned short*)alloc((size_t)BS * D * 2);
  unsigned short* attn = (unsigned short*)alloc((size_t)BS * D * 2);
  float* yb = (float*)alloc((size_t)BS * D * 4);
  float* x1 = (float*)alloc((size_t)BS * D * 4);
  unsigned short* hb = (unsigned short*)alloc((size_t)BS * F * 2);
  unsigned short* x1b = xb;  // reuse: xb dead after QKV GEMM

  // 1) casts + weight transposes (bf16, N x K form)
  cast_f2b<<<(BS * D) / 1024, 256, 0, stream>>>(x, xb, (long)BS * D);
  transpose_f2b<<<dim3(16, 16, 1), 256, 0, stream>>>(Wq, Wqkvt, D, D);
  transpose_f2b<<<dim3(16, 16, 1), 256, 0, stream>>>(Wk, Wqkvt + (size_t)D * D, D, D);
  transpose_f2b<<<dim3(16, 16, 1), 256, 0, stream>>>(Wv, Wqkvt + (size_t)2 * D * D, D, D);
  transpose_f2b<<<dim3(16, 16, 1), 256, 0, stream>>>(Wo, Wot, D, D);
  transpose_f2b<<<dim3(F / 32, D / 32, 1), 256, 0, stream>>>(W1, W1t, F, D);
  transpose_f2b<<<dim3(D / 32, F / 32, 1), 256, 0, stream>>>(W2, W2t, D, F);
  concat3<<<6, 256, 0, stream>>>(bq, bk, bv, bqkv);

  // 2) merged QKV projection: [8192][1536] bf16
  gemm_bt<2, 2, 1, true><<<dim3(BS / 128, N3 / 128, 1), 256, 0, stream>>>(
      xb, Wqkvt, bqkv, QKVb, D, D, D, N3, 0, 0, 0, 0, 0, 0, 1, 1.f);

  // 3) V -> Vt[(b,h), d, s]   (V = QKVb cols 1024..1535)
  transpose_b2b<<<dim3(2, 32, 64), 256, 0, stream>>>(
      QKVb + 1024, Vt, N3, S, (long)S * N3, 64, (long)8 * 64 * S, (long)64 * S, 8);

  // 4-6) fused scores -> entmax -> PV
  fused_attn<<<dim3(64, 64), 256, 0, stream>>>(QKVb, Vt, attn);

  // 7) y = attn_out @ Wo + bo (fp32)
  gemm_bt<2, 2, 1, false><<<dim3(BS / 128, D / 128, 1), 256, 0, stream>>>(
      attn, Wot, bo, yb, D, D, D, D, 0, 0, 0, 0, 0, 0, 1, 1.f);

  // 8) x1 = x + LN(y)*g1 + be1  (fp32 + bf16 copy)
  ln_res<true><<<BS, 256, 0, stream>>>(x, yb, g1, be1, x1, x1b);

  // 9) h = mish(x1 @ W1 + b1) (bf16)
  gemm_bt<2, 2, 2, true><<<dim3(BS / 128, F / 128, 1), 256, 0, stream>>>(
      x1b, W1t, b1, hb, D, D, D, F, 0, 0, 0, 0, 0, 0, 1, 1.f);

  // 10) y2 = h @ W2 + b2 (fp32, reuse yb)
  gemm_bt<2, 2, 1, false><<<dim3(BS / 128, D / 128, 1), 256, 0, stream>>>(
      hb, W2t, b2, yb, F, F, F, D, 0, 0, 0, 0, 0, 0, 1, 1.f);

  // 11) out = x1 + LN(y2)*g2 + be2
  ln_res<false><<<BS, 256, 0, stream>>>(x1, yb, g2, be2, out, nullptr);
}